// Round 11
// baseline (202.270 us; speedup 1.0000x reference)
//
#include <hip/hip_runtime.h>

// Shapes fixed by setup_inputs(): b=8, t=128, k=128, h=4, m=t-1=127.
#define KD 128
#define NH 4
#define MM 127
#define NROWS (1024 * MM)          // 130048 flat kv rows

// ws float offsets
#define OFF_C     0                // [1024][512] c per (bt, h*128+d)  (atomic-published)
#define OFF_FLAGS 524288           // 1024 unsigned flags
#define OFF_WCT   525312           // [256][256][64] per-tile private Wct

#define NCONS 256                  // consumer WGs (proj tiles) — blockIdx 0..255
#define NPROD 1024                 // producer WGs (one per bt)  — blockIdx 256..1279

#define BM 32
#define BN 64
#define BK 64
#define AP 34
#define BP 68
#define SMEM_FLOATS (BK*AP + BK*BP)   // 6528 floats = 26112 B (>= producer's 2576)

typedef unsigned long long ull;

__global__ __launch_bounds__(256, 4)
void mega(const float* __restrict__ q_x,
          const float* __restrict__ kv_x,
          const float* __restrict__ Wk,
          const float* __restrict__ Wq,
          const float* __restrict__ Wv,
          const float* __restrict__ bv,
          float* __restrict__ ws,
          float* __restrict__ out) {
    __shared__ float smem[SMEM_FLOATS];
    const int w   = blockIdx.x;
    const int tid = threadIdx.x;
    unsigned* flags = (unsigned*)(ws + OFF_FLAGS);

    if (w >= NCONS) {
        // ================== PRODUCER: bt = w - NCONS ==================
        const int bt = w - NCONS;
        float* sW1s = smem;            // 512 floats
        float* Zlds = smem + 512;      // 16 floats
        float* Plds = smem + 528;      // 2048 floats

        // inline W1S: sW1s[h][k] = sum_j Wv[129h][j] * Wk[j][k]
        {
            const int h0 = tid >> 7;   // 0/1 -> heads h0, h0+2
            const int k  = tid & 127;
            const float* r0 = Wv + (size_t)(129 * h0) * 256;
            const float* r2 = Wv + (size_t)(129 * (h0 + 2)) * 256;
            float a0 = 0.f, a1 = 0.f;
            #pragma unroll 8
            for (int j = 0; j < 128; ++j) {
                float wk = Wk[j * 128 + k];
                a0 += r0[j] * wk;
                a1 += r2[j] * wk;
            }
            sW1s[h0 * 128 + k]       = a0;
            sW1s[(h0 + 2) * 128 + k] = a1;
        }
        __syncthreads();

        const int wave = tid >> 6;
        const int lane = tid & 63;
        const int dq   = lane & 31;
        const int bit4 = (lane >> 4) & 1;
        const int bit3 = (lane >> 3) & 1;

        float4 w1s[NH];
        #pragma unroll
        for (int h = 0; h < NH; ++h)
            w1s[h] = *(const float4*)&sW1s[h * KD + dq * 4];

        const float4* src = (const float4*)kv_x;
        const size_t rowbase = (size_t)bt * (MM * 32);

        float4 u0 = make_float4(0.f,0.f,0.f,0.f);
        float4 u1 = u0, u2 = u0, u3 = u0, za = u0;

        // one-pass no-max softmax stream (R9-validated math)
        #pragma unroll
        for (int half = 0; half < 2; ++half) {
            const int s = wave + 4 * half;           // slot 0..7, rows s*16..+15
            float4 v[8];
            #pragma unroll
            for (int j = 0; j < 8; ++j) {
                size_t idx = rowbase + (size_t)(s * 16 + 2 * j) * 32 + lane;
                if (idx > (size_t)NROWS * 32 - 1) idx = (size_t)NROWS * 32 - 1;
                v[j] = src[idx];
            }
            #pragma unroll
            for (int j = 0; j < 8; ++j) {
                const int m = s * 16 + 2 * j + (lane >> 5);
                float4 vv = v[j];
                float p0 = vv.x*w1s[0].x + vv.y*w1s[0].y + vv.z*w1s[0].z + vv.w*w1s[0].w;
                float p1 = vv.x*w1s[1].x + vv.y*w1s[1].y + vv.z*w1s[1].z + vv.w*w1s[1].w;
                float p2 = vv.x*w1s[2].x + vv.y*w1s[2].y + vv.z*w1s[2].z + vv.w*w1s[2].w;
                float p3 = vv.x*w1s[3].x + vv.y*w1s[3].y + vv.z*w1s[3].z + vv.w*w1s[3].w;
                float x = bit4 ? p0 : p2;
                float y = bit4 ? p1 : p3;
                float a = (bit4 ? p2 : p0) + __shfl_xor(x, 16);
                float b = (bit4 ? p3 : p1) + __shfl_xor(y, 16);
                float z = bit3 ? a : b;
                float vr = (bit3 ? b : a) + __shfl_xor(z, 8);
                vr += __shfl_xor(vr, 4);
                vr += __shfl_xor(vr, 2);
                vr += __shfl_xor(vr, 1);
                int base = (lane & 32) | (lane & 7);
                float e0 = __expf(__shfl(vr, base));
                float e1 = __expf(__shfl(vr, base | 8));
                float e2 = __expf(__shfl(vr, base | 16));
                float e3 = __expf(__shfl(vr, base | 24));
                float vf = (m < MM) ? 1.f : 0.f;     // kill pad row 127
                e0 *= vf; e1 *= vf; e2 *= vf; e3 *= vf;
                u0.x += e0*vv.x; u0.y += e0*vv.y; u0.z += e0*vv.z; u0.w += e0*vv.w;
                u1.x += e1*vv.x; u1.y += e1*vv.y; u1.z += e1*vv.z; u1.w += e1*vv.w;
                u2.x += e2*vv.x; u2.y += e2*vv.y; u2.z += e2*vv.z; u2.w += e2*vv.w;
                u3.x += e3*vv.x; u3.y += e3*vv.y; u3.z += e3*vv.z; u3.w += e3*vv.w;
                za.x += e0; za.y += e1; za.z += e2; za.w += e3;
            }
        }
        // combine the two 32-lane halves
        u0.x += __shfl_xor(u0.x, 32); u0.y += __shfl_xor(u0.y, 32);
        u0.z += __shfl_xor(u0.z, 32); u0.w += __shfl_xor(u0.w, 32);
        u1.x += __shfl_xor(u1.x, 32); u1.y += __shfl_xor(u1.y, 32);
        u1.z += __shfl_xor(u1.z, 32); u1.w += __shfl_xor(u1.w, 32);
        u2.x += __shfl_xor(u2.x, 32); u2.y += __shfl_xor(u2.y, 32);
        u2.z += __shfl_xor(u2.z, 32); u2.w += __shfl_xor(u2.w, 32);
        u3.x += __shfl_xor(u3.x, 32); u3.y += __shfl_xor(u3.y, 32);
        u3.z += __shfl_xor(u3.z, 32); u3.w += __shfl_xor(u3.w, 32);
        za.x += __shfl_xor(za.x, 32); za.y += __shfl_xor(za.y, 32);
        za.z += __shfl_xor(za.z, 32); za.w += __shfl_xor(za.w, 32);

        if (lane < 32) {
            float* P = Plds + wave * 512;
            *(float4*)&P[0 * KD + dq * 4] = u0;
            *(float4*)&P[1 * KD + dq * 4] = u1;
            *(float4*)&P[2 * KD + dq * 4] = u2;
            *(float4*)&P[3 * KD + dq * 4] = u3;
            if (lane == 0) *(float4*)&Zlds[wave * 4] = za;
        }
        __syncthreads();

        // WG-local combine -> publish c via agent-scope atomics
        if (tid < 128) {
            const int h = tid >> 5;
            float4 s4 = make_float4(0.f,0.f,0.f,0.f);
            float zs = 0.f;
            #pragma unroll
            for (int p = 0; p < 4; ++p) {
                float4 u = *(const float4*)&Plds[p * 512 + tid * 4];
                s4.x += u.x; s4.y += u.y; s4.z += u.z; s4.w += u.w;
                zs += Zlds[p * 4 + h];
            }
            float inv = 1.f / zs;
            s4.x *= inv; s4.y *= inv; s4.z *= inv; s4.w *= inv;
            union { float2 f; ull u; } lo, hi;
            lo.f = make_float2(s4.x, s4.y);
            hi.f = make_float2(s4.z, s4.w);
            ull* dst = (ull*)(ws + OFF_C + (size_t)bt * 512 + tid * 4);
            __hip_atomic_store(dst,     lo.u, __ATOMIC_RELAXED, __HIP_MEMORY_SCOPE_AGENT);
            __hip_atomic_store(dst + 1, hi.u, __ATOMIC_RELAXED, __HIP_MEMORY_SCOPE_AGENT);
        }
        __syncthreads();
        if (tid == 0)
            __hip_atomic_store(&flags[bt], 1u, __ATOMIC_RELEASE, __HIP_MEMORY_SCOPE_AGENT);
        return;
    }

    // ================== CONSUMER: proj tile tt = w ==================
    const int tt  = w;
    const int h   = tt >> 6;                 // 0..3
    const int dd0 = ((tt >> 5) & 1) * BN;    // 0 or 64
    const int r0  = (tt & 31) * BM;          // bt rows r0..r0+31

    // ---- self-compute private Wct tile [256 c][64 dd] -> ws (same-WG readback,
    //      no cross-WG coherence needed; overlaps producers) ----
    {
        const int ddl = tid & 63;
        const int cb  = tid >> 6;            // 0..3 -> c block cb*64..+64
        const int orow = h * 129 + 1 + dd0 + ddl;
        const float* wvp = Wv + (size_t)orow * 256 + ((cb < 2) ? 0 : 128);
        const float* WW  = (cb < 2) ? Wk : Wq;
        float* wct = ws + OFF_WCT + (size_t)tt * 16384;
        #pragma unroll
        for (int h2 = 0; h2 < 2; ++h2) {     // two 32-c halves (reg pressure)
            const int koff = (cb & 1) * 64 + h2 * 32;
            float acc[32];
            #pragma unroll
            for (int i = 0; i < 32; ++i) acc[i] = 0.f;
            #pragma unroll 4
            for (int j = 0; j < 128; ++j) {
                float wvj = wvp[j];
                const float* wkr = WW + j * 128 + koff;   // wave-uniform
                #pragma unroll
                for (int i = 0; i < 32; ++i) acc[i] += wvj * wkr[i];
            }
            #pragma unroll
            for (int i = 0; i < 32; ++i)
                wct[(size_t)(cb * 64 + h2 * 32 + i) * 64 + ddl] = acc[i];
        }
    }

    // ---- wait for my 32 bts (acquire; bounded spin as hang-insurance) ----
    if (tid == 0) {
        unsigned spins = 0;
        for (int r = 0; r < BM; ++r) {
            while (__hip_atomic_load(&flags[r0 + r], __ATOMIC_ACQUIRE,
                                     __HIP_MEMORY_SCOPE_AGENT) == 0u) {
                __builtin_amdgcn_s_sleep(8);
                if (++spins > 4000000u) break;   // ~fail visibly, never hang
            }
        }
    }
    __syncthreads();

    // ---- projection (R4-validated body; A's c-half via agent atomics) ----
    float (*sAT)[AP] = (float (*)[AP])smem;             // [64][34]
    float (*sB)[BP]  = (float (*)[BP])(smem + BK * AP); // [64][68]
    const int tx = tid & 15;
    const int ty = tid >> 4;
    const float* wct = ws + OFF_WCT + (size_t)tt * 16384;

    float acc[2][4];
    #pragma unroll
    for (int i = 0; i < 2; ++i)
        #pragma unroll
        for (int j = 0; j < 4; ++j) acc[i][j] = 0.f;

    for (int ks = 0; ks < 4; ++ks) {
        const int kk0 = ks * BK;
        // stage A transposed: 32 rows x 64 c
        if (kk0 < 128) {
            #pragma unroll
            for (int i = 0; i < 2; ++i) {
                int idx = tid + i * 256;         // 0..511
                int r = idx >> 4, c4 = idx & 15;
                const ull* p = (const ull*)(ws + OFF_C +
                    (size_t)(r0 + r) * 512 + h * KD + kk0 + c4 * 4);
                union { float2 f; ull u; } lo, hi;
                lo.u = __hip_atomic_load(p,     __ATOMIC_RELAXED, __HIP_MEMORY_SCOPE_AGENT);
                hi.u = __hip_atomic_load(p + 1, __ATOMIC_RELAXED, __HIP_MEMORY_SCOPE_AGENT);
                sAT[c4 * 4 + 0][r] = lo.f.x;
                sAT[c4 * 4 + 1][r] = lo.f.y;
                sAT[c4 * 4 + 2][r] = hi.f.x;
                sAT[c4 * 4 + 3][r] = hi.f.y;
            }
        } else {
            #pragma unroll
            for (int i = 0; i < 2; ++i) {
                int idx = tid + i * 256;
                int r = idx >> 4, c4 = idx & 15;
                float4 v = *(const float4*)(q_x +
                    (size_t)(r0 + r) * KD + (kk0 - 128) + c4 * 4);
                sAT[c4 * 4 + 0][r] = v.x;
                sAT[c4 * 4 + 1][r] = v.y;
                sAT[c4 * 4 + 2][r] = v.z;
                sAT[c4 * 4 + 3][r] = v.w;
            }
        }
        // stage B from private wct tile (coalesced, conflict-free)
        #pragma unroll
        for (int i = 0; i < 4; ++i) {
            int idx = tid + i * 256;             // 0..1023
            int c = idx >> 4, d4 = idx & 15;
            *(float4*)&sB[c][d4 * 4] =
                *(const float4*)(wct + (size_t)(kk0 + c) * 64 + d4 * 4);
        }
        __syncthreads();
        #pragma unroll 8
        for (int c = 0; c < BK; ++c) {
            float2 a  = *(const float2*)&sAT[c][ty * 2];
            float4 b4 = *(const float4*)&sB[c][tx * 4];
            acc[0][0] += a.x * b4.x; acc[0][1] += a.x * b4.y;
            acc[0][2] += a.x * b4.z; acc[0][3] += a.x * b4.w;
            acc[1][0] += a.y * b4.x; acc[1][1] += a.y * b4.y;
            acc[1][2] += a.y * b4.z; acc[1][3] += a.y * b4.w;
        }
        __syncthreads();
    }
    // epilogue: + bias, coalesced float4 stores
    float bb[4];
    #pragma unroll
    for (int j = 0; j < 4; ++j) bb[j] = bv[h * 129 + 1 + dd0 + tx * 4 + j];
    #pragma unroll
    for (int i = 0; i < 2; ++i) {
        float4 v;
        v.x = acc[i][0] + bb[0];
        v.y = acc[i][1] + bb[1];
        v.z = acc[i][2] + bb[2];
        v.w = acc[i][3] + bb[3];
        *(float4*)(out + (size_t)(r0 + ty * 2 + i) * 512 + h * KD + dd0 + tx * 4) = v;
    }
}

extern "C" void kernel_launch(void* const* d_in, const int* in_sizes, int n_in,
                              void* d_out, int out_size, void* d_ws, size_t ws_size,
                              hipStream_t stream) {
    const float* q_x  = (const float*)d_in[0];
    const float* kv_x = (const float*)d_in[1];
    const float* Wk   = (const float*)d_in[2];
    const float* Wq   = (const float*)d_in[3];
    const float* Wv   = (const float*)d_in[4];
    const float* bv   = (const float*)d_in[5];
    float* out = (float*)d_out;
    float* ws  = (float*)d_ws;

    // zero the flag array every launch (deterministic; capture-safe)
    hipMemsetAsync((char*)d_ws + (size_t)OFF_FLAGS * 4, 0,
                   NPROD * sizeof(unsigned), stream);
    hipLaunchKernelGGL(mega, dim3(NCONS + NPROD), dim3(256), 0, stream,
                       q_x, kv_x, Wk, Wq, Wv, bv, ws, out);
}